// Round 1
// baseline (1850.374 us; speedup 1.0000x reference)
//
#include <hip/hip_runtime.h>

#define D 64
#define DD (D*D)       // 4096
#define DDD (D*D*D)    // 262144
#define K 27

__global__ __launch_bounds__(256) void deform_conv3d_kernel(
    const float* __restrict__ x,
    const float* __restrict__ kern,   // [27][16][16]
    const float* __restrict__ pk,     // [27][16][81]
    float* __restrict__ out)          // [16][64][64][64]
{
    __shared__ float s_x[16*6*6*6];   // 3456 floats: x halo tile, [c][z6][y6][x6]
    __shared__ float s_off[5184];     // 81*64 offsets; aliased as s_red[4][64][17]

    const int tid  = threadIdx.x;
    const int lane = tid & 63;
    const int wave = __builtin_amdgcn_readfirstlane(tid >> 6);

    const int bx0 = blockIdx.x * 4;
    const int by0 = blockIdx.y * 4;
    const int bz0 = blockIdx.z * 4;

    // ---- Phase 0: load x halo tile (6x6x6 per channel, zero-padded) ----
    for (int i = tid; i < 16*216; i += 256) {
        int c  = i / 216;
        int r  = i - c*216;
        int z6 = r / 36;
        int r2 = r - z6*36;
        int y6 = r2 / 6;
        int x6 = r2 - y6*6;
        int gz = bz0 - 1 + z6;
        int gy = by0 - 1 + y6;
        int gx = bx0 - 1 + x6;
        float v = 0.0f;
        if ((unsigned)gz < D && (unsigned)gy < D && (unsigned)gx < D)
            v = x[c*DDD + gz*DD + gy*D + gx];
        s_x[i] = v;
    }
    __syncthreads();

    // voxel within tile (lane-major: x fastest)
    const int tx = lane & 3, ty = (lane >> 2) & 3, tz = lane >> 4;

    // ---- Phase 1: offset conv. wave w computes o in [obase, obase+21) ----
    // waves 0,1,2 -> obase 0,21,42 ; wave 3 -> 60 (overlap 60..62 recomputed,
    // identical values, benign double-write)
    const int obase = (wave < 3) ? wave*21 : 60;
    float acc[21];
#pragma unroll
    for (int j = 0; j < 21; ++j) acc[j] = 0.0f;

    for (int kt = 0; kt < K; ++kt) {
        const int kd = kt/9, kh = (kt/3)%3, kw = kt%3;
        const float* wrow = pk + kt*(16*81) + obase;
#pragma unroll
        for (int c = 0; c < 16; ++c) {
            float xv = s_x[((c*6 + tz+kd)*6 + ty+kh)*6 + tx+kw];
            const float* wp = wrow + c*81;   // wave-uniform -> s_load
#pragma unroll
            for (int j = 0; j < 21; ++j)
                acc[j] = fmaf(xv, wp[j], acc[j]);
        }
    }
#pragma unroll
    for (int j = 0; j < 21; ++j) {
        int o = obase + j;
        s_off[o*64 + lane] = acc[j];
    }
    __syncthreads();

    // ---- Phase 2: trilinear interp + tap/channel contraction ----
    const int gz = bz0 + tz, gy = by0 + ty, gx = bx0 + tx;
    float oacc[16];
#pragma unroll
    for (int o = 0; o < 16; ++o) oacc[o] = 0.0f;

    const int tbase = wave * 7;        // waves get taps [7w, 7w+7) ∩ [0,27)
    for (int t = 0; t < 7; ++t) {
        int kt = tbase + t;
        if (kt >= K) break;            // wave-uniform exit
        const int kd = kt/9, kh = (kt/3)%3, kw = kt%3;
        float cz = (float)(gz + kd - 1) + s_off[(kt*3+0)*64 + lane];
        float cy = (float)(gy + kh - 1) + s_off[(kt*3+1)*64 + lane];
        float cx = (float)(gx + kw - 1) + s_off[(kt*3+2)*64 + lane];
        float zf = floorf(cz), yf = floorf(cy), xf = floorf(cx);
        float fz = cz - zf, fy = cy - yf, fx = cx - xf;
        int z0 = (int)zf, y0 = (int)yf, x0 = (int)xf;

        float val[16];
#pragma unroll
        for (int c = 0; c < 16; ++c) val[c] = 0.0f;

#pragma unroll
        for (int dz = 0; dz < 2; ++dz) {
            int zi = z0 + dz;
            if ((unsigned)zi >= D) continue;
            float wz = dz ? fz : 1.0f - fz;
#pragma unroll
            for (int dy = 0; dy < 2; ++dy) {
                int yi = y0 + dy;
                if ((unsigned)yi >= D) continue;
                float wy = dy ? fy : 1.0f - fy;
#pragma unroll
                for (int dx = 0; dx < 2; ++dx) {
                    int xi = x0 + dx;
                    if ((unsigned)xi >= D) continue;
                    float w = wz * wy * (dx ? fx : 1.0f - fx);
                    int base = zi*DD + yi*D + xi;
#pragma unroll
                    for (int c = 0; c < 16; ++c)
                        val[c] = fmaf(w, x[c*DDD + base], val[c]);
                }
            }
        }
        const float* kp = kern + kt*(16*16);   // wave-uniform -> s_load
#pragma unroll
        for (int c = 0; c < 16; ++c) {
            float vc = val[c];
#pragma unroll
            for (int o = 0; o < 16; ++o)
                oacc[o] = fmaf(vc, kp[c*16+o], oacc[o]);
        }
    }

    // ---- Reduce partial outputs across the 4 tap-group waves ----
    __syncthreads();                 // all s_off reads done; reuse as s_red
    float* s_red = s_off;            // [4][64][17] (stride 17: conflict-free)
#pragma unroll
    for (int o = 0; o < 16; ++o)
        s_red[(wave*64 + lane)*17 + o] = oacc[o];
    __syncthreads();

#pragma unroll
    for (int j = 0; j < 4; ++j) {
        int o = wave*4 + j;
        float s = s_red[(0*64 + lane)*17 + o]
                + s_red[(1*64 + lane)*17 + o]
                + s_red[(2*64 + lane)*17 + o]
                + s_red[(3*64 + lane)*17 + o];
        out[o*DDD + gz*DD + gy*D + gx] = s;
    }
}

extern "C" void kernel_launch(void* const* d_in, const int* in_sizes, int n_in,
                              void* d_out, int out_size, void* d_ws, size_t ws_size,
                              hipStream_t stream) {
    const float* x    = (const float*)d_in[0];
    const float* kern = (const float*)d_in[1];
    const float* pk   = (const float*)d_in[2];
    float* out = (float*)d_out;
    dim3 grid(16, 16, 16);
    deform_conv3d_kernel<<<grid, 256, 0, stream>>>(x, kern, pk, out);
}

// Round 2
// 570.908 us; speedup vs baseline: 3.2411x; 3.2411x over previous
//
#include <hip/hip_runtime.h>

#define D 64
#define DD (D*D)       // 4096
#define DDD (D*D*D)    // 262144
#define K 27

// Halo layout: [c][z8][y8][x padded to 9] floats, halo origin = tile origin - 2.
// 16*8*8*9 = 9216 floats = 36 KB -> 4 blocks/CU.
#define HPAD 9
#define HROW 72        // 8*9
#define HCH  576       // 8*8*9

__global__ __launch_bounds__(256, 4) void deform_conv3d_kernel(
    const float* __restrict__ x,
    const float* __restrict__ kern,   // [27][16][16]
    const float* __restrict__ pk,     // [27][16][81]
    float* __restrict__ out)          // [16][64][64][64]
{
    __shared__ float s_h[16 * HCH];   // x halo; reused as reduction buffer at end

    const int tid  = threadIdx.x;
    const int lane = tid & 63;
    const int wave = __builtin_amdgcn_readfirstlane(tid >> 6);

    const int bx0 = blockIdx.x * 4;
    const int by0 = blockIdx.y * 4;
    const int bz0 = blockIdx.z * 4;

    // ---- Phase 0: load 8^3 x-halo per channel (zero outside volume) ----
    for (int i = tid; i < 16 * 512; i += 256) {
        int c  = i >> 9;
        int r  = i & 511;
        int z  = r >> 6;
        int y  = (r >> 3) & 7;
        int xx = r & 7;
        int gz = bz0 - 2 + z;
        int gy = by0 - 2 + y;
        int gx = bx0 - 2 + xx;
        float v = 0.0f;
        if ((unsigned)gz < D && (unsigned)gy < D && (unsigned)gx < D)
            v = x[c*DDD + gz*DD + gy*D + gx];
        s_h[c*HCH + z*HROW + y*HPAD + xx] = v;
    }
    __syncthreads();

    const int tx = lane & 3, ty = (lane >> 2) & 3, tz = lane >> 4;

    // ---- Phase 1: offset conv, offsets stay in registers ----
    // wave 0,1,2 -> o in [21w, 21w+21); wave 3 -> o in [60, 81)
    const int obase = (wave < 3) ? wave * 21 : 60;
    float acc[21];
#pragma unroll
    for (int j = 0; j < 21; ++j) acc[j] = 0.0f;

    for (int kt = 0; kt < K; ++kt) {
        const int kd = kt / 9, kh = (kt / 3) % 3, kw = kt % 3;
        const float* wrow = pk + kt * (16 * 81) + obase;   // wave-uniform
        // phase-1 sample (gz+kd-1) -> halo idx (tz+kd+1), range 1..6
        const int hb = (tz + kd + 1) * HROW + (ty + kh + 1) * HPAD + (tx + kw + 1);
#pragma unroll
        for (int c = 0; c < 16; ++c) {
            float xv = s_h[c*HCH + hb];
            const float* wp = wrow + c * 81;               // wave-uniform -> s_load
#pragma unroll
            for (int j = 0; j < 21; ++j)
                acc[j] = fmaf(xv, wp[j], acc[j]);
        }
    }

    // wave 3 computed o=60..80 but its phase-2 taps (21..26) need o=63..80:
    // shift so acc[3t+coord] maps to tap (7*wave + t) for every wave.
    if (wave == 3) {
#pragma unroll
        for (int j = 0; j < 18; ++j) acc[j] = acc[j + 3];
    }

    // ---- Phase 2: trilinear interp from LDS halo + tap/channel contraction ----
    const int gz = bz0 + tz, gy = by0 + ty, gx = bx0 + tx;
    float oacc[16];
#pragma unroll
    for (int o = 0; o < 16; ++o) oacc[o] = 0.0f;

    const int ntaps = (wave < 3) ? 7 : 6;
    const int tbase = wave * 7;          // wave3 -> 21

#pragma unroll
    for (int t = 0; t < 7; ++t) {
        if (t < ntaps) {                 // wave-uniform guard
            const int kt = tbase + t;
            const int kd = kt / 9, kh = (kt / 3) % 3, kw = kt % 3;
            float cz = (float)(gz + kd - 1) + acc[3*t + 0];
            float cy = (float)(gy + kh - 1) + acc[3*t + 1];
            float cx = (float)(gx + kw - 1) + acc[3*t + 2];
            float zf = floorf(cz), yf = floorf(cy), xf = floorf(cx);
            float fz = cz - zf, fy = cy - yf, fx = cx - xf;
            int z0 = (int)zf, y0 = (int)yf, x0 = (int)xf;

            float val[16];
#pragma unroll
            for (int c = 0; c < 16; ++c) val[c] = 0.0f;

#pragma unroll
            for (int dz = 0; dz < 2; ++dz) {
                int zi = z0 + dz;
                float wz = dz ? fz : 1.0f - fz;
#pragma unroll
                for (int dy = 0; dy < 2; ++dy) {
                    int yi = y0 + dy;
                    float wy = dy ? fy : 1.0f - fy;
#pragma unroll
                    for (int dx = 0; dx < 2; ++dx) {
                        int xi = x0 + dx;
                        if ((unsigned)zi < D && (unsigned)yi < D && (unsigned)xi < D) {
                            float w = wz * wy * (dx ? fx : 1.0f - fx);
                            int hz = zi - bz0 + 2, hy = yi - by0 + 2, hx = xi - bx0 + 2;
                            if ((unsigned)(hz | hy | hx) < 8u) {
                                // fast path: sample from LDS halo
                                int hb = hz*HROW + hy*HPAD + hx;
#pragma unroll
                                for (int c = 0; c < 16; ++c)
                                    val[c] = fmaf(w, s_h[c*HCH + hb], val[c]);
                            } else {
                                // rare: offset pushed corner outside halo
                                int gb = zi*DD + yi*D + xi;
#pragma unroll
                                for (int c = 0; c < 16; ++c)
                                    val[c] = fmaf(w, x[c*DDD + gb], val[c]);
                            }
                        }
                    }
                }
            }
            const float* kp = kern + kt * (16 * 16);   // wave-uniform -> s_load
#pragma unroll
            for (int c = 0; c < 16; ++c) {
                float vc = val[c];
#pragma unroll
                for (int o = 0; o < 16; ++o)
                    oacc[o] = fmaf(vc, kp[c*16 + o], oacc[o]);
            }
        }
    }

    // ---- Reduce partial outputs across the 4 waves (reuse s_h) ----
    __syncthreads();                 // everyone done reading the halo
    float* s_red = s_h;              // [256][17] stride-17: conflict-free
#pragma unroll
    for (int o = 0; o < 16; ++o)
        s_red[(wave*64 + lane)*17 + o] = oacc[o];
    __syncthreads();

#pragma unroll
    for (int j = 0; j < 4; ++j) {
        int o = wave*4 + j;
        float s = s_red[(0*64 + lane)*17 + o]
                + s_red[(1*64 + lane)*17 + o]
                + s_red[(2*64 + lane)*17 + o]
                + s_red[(3*64 + lane)*17 + o];
        out[o*DDD + gz*DD + gy*D + gx] = s;
    }
}

extern "C" void kernel_launch(void* const* d_in, const int* in_sizes, int n_in,
                              void* d_out, int out_size, void* d_ws, size_t ws_size,
                              hipStream_t stream) {
    const float* x    = (const float*)d_in[0];
    const float* kern = (const float*)d_in[1];
    const float* pk   = (const float*)d_in[2];
    float* out = (float*)d_out;
    dim3 grid(16, 16, 16);
    deform_conv3d_kernel<<<grid, 256, 0, stream>>>(x, kern, pk, out);
}

// Round 3
// 204.059 us; speedup vs baseline: 9.0678x; 2.7978x over previous
//
#include <hip/hip_runtime.h>

#define D 64
#define DD 4096
#define DDD 262144
#define K 27

typedef __bf16  bf16x8 __attribute__((ext_vector_type(8)));
typedef float   f32x4  __attribute__((ext_vector_type(4)));
typedef float   f32x2  __attribute__((ext_vector_type(2)));
typedef unsigned int u32x4 __attribute__((ext_vector_type(4)));

// tile 16x2x2 voxels; halo = tile + 2 on each side
#define HX 20
#define HY 6
#define HZ 6
#define HSP 720          // HZ*HY*HX spatial slots
#define CPAD 24          // bf16 per voxel slot (16 used, pad to 48B for banks+align)
#define SOSTR 66         // s_off leading-dim pad

// ---------------- prep 1: pk -> A-fragment-linear bf16 W ----------------
// W_sw layout: [s=0..13][mt=0..5][lane=0..63] 8 bf16 each (16B chunk).
// chunk(t = (s*6+mt)*64+lane): m = 16mt + (lane&15); k = 32s + 8*(lane>>4) + j
// W[m][k] = pk[kt][c][m], k = kt*16+c; zero-pad kt>=27 or m>=81.
__global__ __launch_bounds__(256) void prep_w(const float* __restrict__ pk,
                                              __bf16* __restrict__ Wsw) {
    int t = blockIdx.x * 256 + threadIdx.x;
    if (t >= 14 * 6 * 64) return;
    int lane = t & 63;
    int sm = t >> 6;
    int s = sm / 6, mt = sm - 6 * s;
    int m = mt * 16 + (lane & 15);
    int q = lane >> 4;
    bf16x8 v;
#pragma unroll
    for (int j = 0; j < 8; ++j) {
        int k = 32 * s + 8 * q + j;
        int kt = k >> 4, c = k & 15;
        float w = (kt < K && m < 81) ? pk[kt * 1296 + c * 81 + m] : 0.0f;
        v[j] = (__bf16)w;
    }
    *(bf16x8*)(Wsw + t * 8) = v;
}

// ---------------- prep 2: x -> channel-last bf16 ----------------
__global__ __launch_bounds__(256) void prep_xcl(const float* __restrict__ x,
                                                __bf16* __restrict__ xcl) {
    int v = blockIdx.x * 256 + threadIdx.x;     // 262144 voxels
    const float* xp = x + v;
    bf16x8 a, b;
#pragma unroll
    for (int c = 0; c < 8; ++c) a[c] = (__bf16)xp[c * DDD];
#pragma unroll
    for (int c = 0; c < 8; ++c) b[c] = (__bf16)xp[(c + 8) * DDD];
    *(bf16x8*)(xcl + v * 16)     = a;
    *(bf16x8*)(xcl + v * 16 + 8) = b;
}

// ---------------- main fused kernel ----------------
template <bool XCL>
__global__ __launch_bounds__(256, 3) void deform_main(
    const float* __restrict__ x,          // [16][64][64][64] fp32
    const float* __restrict__ kern,       // [27][16][16] fp32
    const __bf16* __restrict__ Wsw,       // A-frag-linear offset weights
    const __bf16* __restrict__ xcl,       // channel-last bf16 x (if XCL)
    float* __restrict__ out)              // [16][64][64][64]
{
    __shared__ __bf16 s_h[HSP * CPAD];    // 34560 B halo, channel-last bf16
    __shared__ __bf16 s_off[81 * SOSTR];  // 10692 B offsets bf16

    const int tid  = threadIdx.x;
    const int lane = tid & 63;
    const int wave = __builtin_amdgcn_readfirstlane(tid >> 6);

    const int bx0 = blockIdx.x * 16;
    const int by0 = blockIdx.y * 2;
    const int bz0 = blockIdx.z * 2;

    // ---- Phase 0: stage halo (zero outside volume), channel-last bf16 ----
    for (int i = tid; i < HSP; i += 256) {
        int z = i / 120;
        int r = i - z * 120;
        int y = r / 20;
        int xx = r - y * 20;
        int gz = bz0 - 2 + z, gy = by0 - 2 + y, gx = bx0 - 2 + xx;
        bool in = (unsigned)gz < D && (unsigned)gy < D && (unsigned)gx < D;
        bf16x8 a = {}, b = {};
        if (XCL) {
            if (in) {
                const __bf16* p = xcl + (size_t)(gz * DD + gy * D + gx) * 16;
                a = *(const bf16x8*)p;
                b = *(const bf16x8*)(p + 8);
            }
        } else {
            if (in) {
                const float* p = x + (gz * DD + gy * D + gx);
#pragma unroll
                for (int c = 0; c < 8; ++c) a[c] = (__bf16)p[c * DDD];
#pragma unroll
                for (int c = 0; c < 8; ++c) b[c] = (__bf16)p[(c + 8) * DDD];
            }
        }
        *(bf16x8*)(s_h + i * CPAD)     = a;
        *(bf16x8*)(s_h + i * CPAD + 8) = b;
    }
    __syncthreads();

    // ---- Phase 1: offset conv as bf16 MFMA implicit GEMM ----
    // wave w handles N-tile voxels v = 16w + n, n = lane&15.
    // voxel (tz,ty,tx): tz = v>>5, ty = (v>>4)&1, tx = v&15.
    {
        const int n = lane & 15, q = lane >> 4;
        const int vtz = wave >> 1, vty = wave & 1;    // tx = n
        f32x4 acc[6] = {};
        for (int s = 0; s < 14; ++s) {
            int kt = 2 * s + (q >> 1);                // tap for this quad's k-range
            int ktc = (kt < K) ? kt : 0;              // pad taps: W rows are zero
            int kd = ktc / 9, kh = (ktc / 3) % 3, kw = ktc % 3;
            int idx = (vtz + kd + 1) * 120 + (vty + kh + 1) * 20 + (n + kw + 1);
            bf16x8 bfrag = *(const bf16x8*)(s_h + idx * CPAD + (q & 1) * 8);
#pragma unroll
            for (int mt = 0; mt < 6; ++mt) {
                bf16x8 afrag = *(const bf16x8*)(Wsw + ((s * 6 + mt) * 64 + lane) * 8);
                acc[mt] = __builtin_amdgcn_mfma_f32_16x16x32_bf16(afrag, bfrag, acc[mt], 0, 0, 0);
            }
        }
        // D layout: col(lane&15)=voxel n, row = q*4 + r within tile mt
        const int v = wave * 16 + n;
#pragma unroll
        for (int mt = 0; mt < 6; ++mt)
#pragma unroll
            for (int r = 0; r < 4; ++r) {
                int o = mt * 16 + q * 4 + r;
                if (o < 81) s_off[o * SOSTR + v] = (__bf16)acc[mt][r];
            }
    }
    __syncthreads();

    // ---- Phase 2: trilinear interp (LDS, bf16 channel-last) + contraction ----
    const int tx = lane & 15, ty = (lane >> 4) & 1, tz = lane >> 5;
    const int gz = bz0 + tz, gy = by0 + ty, gx = bx0 + tx;
    f32x2 oacc[8] = {};

    const int ntaps = (wave < 3) ? 7 : 6;
    for (int t = 0; t < ntaps; ++t) {
        const int kt = wave * 7 + t;
        const int kd = kt / 9, kh = (kt / 3) % 3, kw = kt % 3;
        float cz = (float)(gz + kd - 1) + (float)s_off[(3 * kt + 0) * SOSTR + lane];
        float cy = (float)(gy + kh - 1) + (float)s_off[(3 * kt + 1) * SOSTR + lane];
        float cx = (float)(gx + kw - 1) + (float)s_off[(3 * kt + 2) * SOSTR + lane];
        float zf = floorf(cz), yf = floorf(cy), xf = floorf(cx);
        float fz = cz - zf, fy = cy - yf, fx = cx - xf;
        int z0 = (int)zf, y0 = (int)yf, x0 = (int)xf;
        int hz0 = z0 - bz0 + 2, hy0 = y0 - by0 + 2, hx0 = x0 - bx0 + 2;

        f32x2 val[8] = {};
        if ((unsigned)hz0 < 5u && (unsigned)hy0 < 5u && (unsigned)hx0 < 19u) {
            // all 8 corners inside halo (out-of-volume corners hold 0)
#pragma unroll
            for (int dz = 0; dz < 2; ++dz) {
                float wz = dz ? fz : 1.0f - fz;
#pragma unroll
                for (int dy = 0; dy < 2; ++dy) {
                    float wzy = wz * (dy ? fy : 1.0f - fy);
#pragma unroll
                    for (int dx = 0; dx < 2; ++dx) {
                        float w = wzy * (dx ? fx : 1.0f - fx);
                        int idx = (hz0 + dz) * 120 + (hy0 + dy) * 20 + (hx0 + dx);
                        bf16x8 c0 = *(const bf16x8*)(s_h + idx * CPAD);
                        bf16x8 c1 = *(const bf16x8*)(s_h + idx * CPAD + 8);
                        u32x4 u0 = __builtin_bit_cast(u32x4, c0);
                        u32x4 u1 = __builtin_bit_cast(u32x4, c1);
                        f32x2 w2 = {w, w};
#pragma unroll
                        for (int d = 0; d < 4; ++d) {
                            unsigned int u = u0[d];
                            f32x2 h;
                            h.x = __builtin_bit_cast(float, u << 16);
                            h.y = __builtin_bit_cast(float, u & 0xffff0000u);
                            val[d] += w2 * h;
                        }
#pragma unroll
                        for (int d = 0; d < 4; ++d) {
                            unsigned int u = u1[d];
                            f32x2 h;
                            h.x = __builtin_bit_cast(float, u << 16);
                            h.y = __builtin_bit_cast(float, u & 0xffff0000u);
                            val[d + 4] += w2 * h;
                        }
                    }
                }
            }
        } else {
            // rare: offset >= 1 voxel pushed a corner outside the halo
#pragma unroll
            for (int dz = 0; dz < 2; ++dz) {
                int zi = z0 + dz;
                float wz = dz ? fz : 1.0f - fz;
#pragma unroll
                for (int dy = 0; dy < 2; ++dy) {
                    int yi = y0 + dy;
                    float wzy = wz * (dy ? fy : 1.0f - fy);
#pragma unroll
                    for (int dx = 0; dx < 2; ++dx) {
                        int xi = x0 + dx;
                        if ((unsigned)zi < D && (unsigned)yi < D && (unsigned)xi < D) {
                            float w = wzy * (dx ? fx : 1.0f - fx);
                            int base = zi * DD + yi * D + xi;
#pragma unroll
                            for (int c = 0; c < 16; ++c)
                                val[c >> 1][c & 1] += w * x[c * DDD + base];
                        }
                    }
                }
            }
        }
        const float* kp = kern + kt * 256;            // wave-uniform -> s_load
#pragma unroll
        for (int c = 0; c < 16; ++c) {
            float vc = val[c >> 1][c & 1];
            f32x2 vc2 = {vc, vc};
            const f32x2* kp2 = (const f32x2*)(kp + c * 16);
#pragma unroll
            for (int j = 0; j < 8; ++j)
                oacc[j] += vc2 * kp2[j];
        }
    }

    // ---- cross-wave reduction (reuse halo LDS) ----
    __syncthreads();
    float* s_red = (float*)s_h;                       // 256*17 floats
#pragma unroll
    for (int o = 0; o < 16; ++o)
        s_red[(wave * 64 + lane) * 17 + o] = oacc[o >> 1][o & 1];
    __syncthreads();

#pragma unroll
    for (int j = 0; j < 4; ++j) {
        int o = wave * 4 + j;
        float s = s_red[(0 * 64 + lane) * 17 + o]
                + s_red[(1 * 64 + lane) * 17 + o]
                + s_red[(2 * 64 + lane) * 17 + o]
                + s_red[(3 * 64 + lane) * 17 + o];
        out[o * DDD + gz * DD + gy * D + gx] = s;
    }
}

extern "C" void kernel_launch(void* const* d_in, const int* in_sizes, int n_in,
                              void* d_out, int out_size, void* d_ws, size_t ws_size,
                              hipStream_t stream) {
    const float* x    = (const float*)d_in[0];
    const float* kern = (const float*)d_in[1];
    const float* pk   = (const float*)d_in[2];
    float* out = (float*)d_out;

    __bf16* Wsw = (__bf16*)d_ws;                       // 86016 B
    __bf16* xcl = (__bf16*)((char*)d_ws + 131072);     // 8 MB channel-last x
    const size_t need_xcl = 131072 + (size_t)DDD * 16 * 2;
    const bool use_xcl = ws_size >= need_xcl;

    prep_w<<<21, 256, 0, stream>>>(pk, Wsw);
    if (use_xcl) {
        prep_xcl<<<1024, 256, 0, stream>>>(x, xcl);
        deform_main<true><<<dim3(4, 32, 32), 256, 0, stream>>>(x, kern, Wsw, xcl, out);
    } else {
        deform_main<false><<<dim3(4, 32, 32), 256, 0, stream>>>(x, kern, Wsw, nullptr, out);
    }
}

// Round 4
// 202.569 us; speedup vs baseline: 9.1345x; 1.0074x over previous
//
#include <hip/hip_runtime.h>

#define D 64
#define DD 4096
#define DDD 262144
#define K 27

typedef __bf16  bf16x8 __attribute__((ext_vector_type(8)));
typedef float   f32x4  __attribute__((ext_vector_type(4)));
typedef float   f32x2  __attribute__((ext_vector_type(2)));
typedef unsigned int u32x4 __attribute__((ext_vector_type(4)));

// tile 8x4x2 voxels (x,y,z); halo = tile + 2 each side
#define HX 12
#define HY 8
#define HZ 6
#define HROW 12          // x extent
#define HPLN 96          // HY*HX
#define HSP  576         // HZ*HY*HX spatial slots
#define CPAD 24          // bf16 per voxel slot (16 used; 48B: b128-aligned, bank-clean)

// ---------------- prep: x -> channel-last bf16  (+ blocks 0..20: pk -> Wsw) ----
// Wsw layout: [s=0..13][mt=0..5][lane=0..63] 8 bf16 each (16B chunk).
// chunk(t=(s*6+mt)*64+lane): m = 16mt + (lane&15); k = 32s + 8*(lane>>4) + j
// W[m][k] = pk[kt][c][m], k = kt*16+c; zero-pad kt>=27 or m>=81.
__global__ __launch_bounds__(256) void prep_fused(const float* __restrict__ x,
                                                  const float* __restrict__ pk,
                                                  __bf16* __restrict__ Wsw,
                                                  __bf16* __restrict__ xcl) {
    int v = blockIdx.x * 256 + threadIdx.x;     // 262144 voxels
    const float* xp = x + v;
    bf16x8 a, b;
#pragma unroll
    for (int c = 0; c < 8; ++c) a[c] = (__bf16)xp[c * DDD];
#pragma unroll
    for (int c = 0; c < 8; ++c) b[c] = (__bf16)xp[(c + 8) * DDD];
    *(bf16x8*)(xcl + v * 16)     = a;
    *(bf16x8*)(xcl + v * 16 + 8) = b;

    int t = v;                                   // blocks 0..20 also build Wsw
    if (t < 14 * 6 * 64) {
        int lane = t & 63;
        int sm = t >> 6;
        int s = sm / 6, mt = sm - 6 * s;
        int m = mt * 16 + (lane & 15);
        int q = lane >> 4;
        bf16x8 w;
#pragma unroll
        for (int j = 0; j < 8; ++j) {
            int k = 32 * s + 8 * q + j;
            int kt = k >> 4, c = k & 15;
            float wv = (kt < K && m < 81) ? pk[kt * 1296 + c * 81 + m] : 0.0f;
            w[j] = (__bf16)wv;
        }
        *(bf16x8*)(Wsw + t * 8) = w;
    }
}

__global__ __launch_bounds__(256) void prep_w_only(const float* __restrict__ pk,
                                                   __bf16* __restrict__ Wsw) {
    int t = blockIdx.x * 256 + threadIdx.x;
    if (t >= 14 * 6 * 64) return;
    int lane = t & 63;
    int sm = t >> 6;
    int s = sm / 6, mt = sm - 6 * s;
    int m = mt * 16 + (lane & 15);
    int q = lane >> 4;
    bf16x8 w;
#pragma unroll
    for (int j = 0; j < 8; ++j) {
        int k = 32 * s + 8 * q + j;
        int kt = k >> 4, c = k & 15;
        float wv = (kt < K && m < 81) ? pk[kt * 1296 + c * 81 + m] : 0.0f;
        w[j] = (__bf16)wv;
    }
    *(bf16x8*)(Wsw + t * 8) = w;
}

// ---------------- main fused kernel ----------------
template <bool XCL>
__global__ __launch_bounds__(256, 4) void deform_main(
    const float* __restrict__ x,          // [16][64][64][64] fp32
    const float* __restrict__ kern,       // [27][16][16] fp32
    const __bf16* __restrict__ Wsw,       // A-frag-linear offset weights
    const __bf16* __restrict__ xcl,       // channel-last bf16 x (if XCL)
    float* __restrict__ out)              // [16][64][64][64]
{
    __shared__ __bf16 s_h[HSP * CPAD];    // 27648 B halo; reused for reduction
    __shared__ __bf16 s_off[81 * 64];     // 10368 B offsets bf16

    const int tid  = threadIdx.x;
    const int lane = tid & 63;
    const int wave = __builtin_amdgcn_readfirstlane(tid >> 6);

    const int bx0 = blockIdx.x * 8;
    const int by0 = blockIdx.y * 4;
    const int bz0 = blockIdx.z * 2;

    // ---- Phase 0: stage halo (zero outside volume), channel-last bf16 ----
    for (int i = tid; i < HSP; i += 256) {
        int z = i / HPLN;
        int r = i - z * HPLN;
        int y = r / HROW;
        int xx = r - y * HROW;
        int gz = bz0 - 2 + z, gy = by0 - 2 + y, gx = bx0 - 2 + xx;
        bool in = (unsigned)gz < D && (unsigned)gy < D && (unsigned)gx < D;
        bf16x8 a = {}, b = {};
        if (XCL) {
            if (in) {
                const __bf16* p = xcl + (size_t)(gz * DD + gy * D + gx) * 16;
                a = *(const bf16x8*)p;
                b = *(const bf16x8*)(p + 8);
            }
        } else {
            if (in) {
                const float* p = x + (gz * DD + gy * D + gx);
#pragma unroll
                for (int c = 0; c < 8; ++c) a[c] = (__bf16)p[c * DDD];
#pragma unroll
                for (int c = 0; c < 8; ++c) b[c] = (__bf16)p[(c + 8) * DDD];
            }
        }
        *(bf16x8*)(s_h + i * CPAD)     = a;
        *(bf16x8*)(s_h + i * CPAD + 8) = b;
    }
    __syncthreads();

    // ---- Phase 1: offset conv as bf16 MFMA implicit GEMM (M=96,K=448,N=64) ----
    // wave w owns N-voxels v = 16w + n, n = lane&15.
    // v -> (tz,ty,tx): tz = w>>1, ty = 2*(w&1) + (n>>3), tx = n&7.
    {
        const int n = lane & 15, q = lane >> 4;
        const int vtz = wave >> 1;
        const int vty = 2 * (wave & 1) + (n >> 3);
        const int vtx = n & 7;
        f32x4 acc[6] = {};
        for (int s = 0; s < 14; ++s) {
            int kt = 2 * s + (q >> 1);
            int ktc = (kt < K) ? kt : 0;              // pad taps: W rows are zero
            int kd = ktc / 9, kh = (ktc / 3) % 3, kw = ktc % 3;
            int idx = (vtz + kd + 1) * HPLN + (vty + kh + 1) * HROW + (vtx + kw + 1);
            bf16x8 bfrag = *(const bf16x8*)(s_h + idx * CPAD + (q & 1) * 8);
#pragma unroll
            for (int mt = 0; mt < 6; ++mt) {
                bf16x8 afrag = *(const bf16x8*)(Wsw + ((s * 6 + mt) * 64 + lane) * 8);
                acc[mt] = __builtin_amdgcn_mfma_f32_16x16x32_bf16(afrag, bfrag, acc[mt], 0, 0, 0);
            }
        }
        // D layout: col(lane&15)=voxel n, row = q*4 + r within tile mt
        const int v = wave * 16 + n;
#pragma unroll
        for (int mt = 0; mt < 6; ++mt)
#pragma unroll
            for (int r = 0; r < 4; ++r) {
                int o = mt * 16 + q * 4 + r;
                if (o < 81) s_off[o * 64 + v] = (__bf16)acc[mt][r];
            }
    }
    __syncthreads();

    // ---- Phase 2: trilinear interp (LDS bf16 channel-last) + contraction ----
    const int tx = lane & 7, ty = (lane >> 3) & 3, tz = lane >> 5;
    const int gz = bz0 + tz, gy = by0 + ty, gx = bx0 + tx;
    f32x2 oacc[8] = {};

    const int ntaps = (wave < 3) ? 7 : 6;
    for (int t = 0; t < ntaps; ++t) {
        const int kt = wave * 7 + t;
        const int kd = kt / 9, kh = (kt / 3) % 3, kw = kt % 3;
        float cz = (float)(gz + kd - 1) + (float)s_off[(3 * kt + 0) * 64 + lane];
        float cy = (float)(gy + kh - 1) + (float)s_off[(3 * kt + 1) * 64 + lane];
        float cx = (float)(gx + kw - 1) + (float)s_off[(3 * kt + 2) * 64 + lane];
        float zf = floorf(cz), yf = floorf(cy), xf = floorf(cx);
        float fz = cz - zf, fy = cy - yf, fx = cx - xf;
        int z0 = (int)zf, y0 = (int)yf, x0 = (int)xf;
        int hz0 = z0 - bz0 + 2, hy0 = y0 - by0 + 2, hx0 = x0 - bx0 + 2;

        f32x2 val[8] = {};
        if ((unsigned)hz0 < (unsigned)(HZ - 1) && (unsigned)hy0 < (unsigned)(HY - 1)
            && (unsigned)hx0 < (unsigned)(HX - 1)) {
            // all 8 corners inside halo (out-of-volume corners hold 0)
#pragma unroll
            for (int dz = 0; dz < 2; ++dz) {
                float wz = dz ? fz : 1.0f - fz;
#pragma unroll
                for (int dy = 0; dy < 2; ++dy) {
                    float wzy = wz * (dy ? fy : 1.0f - fy);
#pragma unroll
                    for (int dx = 0; dx < 2; ++dx) {
                        float w = wzy * (dx ? fx : 1.0f - fx);
                        int idx = (hz0 + dz) * HPLN + (hy0 + dy) * HROW + (hx0 + dx);
                        bf16x8 c0 = *(const bf16x8*)(s_h + idx * CPAD);
                        bf16x8 c1 = *(const bf16x8*)(s_h + idx * CPAD + 8);
                        u32x4 u0 = __builtin_bit_cast(u32x4, c0);
                        u32x4 u1 = __builtin_bit_cast(u32x4, c1);
                        f32x2 w2 = {w, w};
#pragma unroll
                        for (int d = 0; d < 4; ++d) {
                            unsigned int u = u0[d];
                            f32x2 h;
                            h.x = __builtin_bit_cast(float, u << 16);
                            h.y = __builtin_bit_cast(float, u & 0xffff0000u);
                            val[d] += w2 * h;
                        }
#pragma unroll
                        for (int d = 0; d < 4; ++d) {
                            unsigned int u = u1[d];
                            f32x2 h;
                            h.x = __builtin_bit_cast(float, u << 16);
                            h.y = __builtin_bit_cast(float, u & 0xffff0000u);
                            val[d + 4] += w2 * h;
                        }
                    }
                }
            }
        } else {
            // rare: |offset| >= 1 pushed a corner outside the halo
#pragma unroll
            for (int dz = 0; dz < 2; ++dz) {
                int zi = z0 + dz;
                float wz = dz ? fz : 1.0f - fz;
#pragma unroll
                for (int dy = 0; dy < 2; ++dy) {
                    int yi = y0 + dy;
                    float wzy = wz * (dy ? fy : 1.0f - fy);
#pragma unroll
                    for (int dx = 0; dx < 2; ++dx) {
                        int xi = x0 + dx;
                        if ((unsigned)zi < D && (unsigned)yi < D && (unsigned)xi < D) {
                            float w = wzy * (dx ? fx : 1.0f - fx);
                            int base = zi * DD + yi * D + xi;
#pragma unroll
                            for (int c = 0; c < 16; ++c)
                                val[c >> 1][c & 1] += w * x[c * DDD + base];
                        }
                    }
                }
            }
        }
        const float* kp = kern + kt * 256;            // wave-uniform -> s_load
#pragma unroll
        for (int c = 0; c < 16; ++c) {
            float vc = val[c >> 1][c & 1];
            f32x2 vc2 = {vc, vc};
            const f32x2* kp2 = (const f32x2*)(kp + c * 16);
#pragma unroll
            for (int j = 0; j < 8; ++j)
                oacc[j] += vc2 * kp2[j];
        }
    }

    // ---- cross-wave reduction (reuse halo LDS) ----
    __syncthreads();
    float* s_red = (float*)s_h;                       // 256*17 floats = 17408 B
#pragma unroll
    for (int o = 0; o < 16; ++o)
        s_red[(wave * 64 + lane) * 17 + o] = oacc[o >> 1][o & 1];
    __syncthreads();

#pragma unroll
    for (int j = 0; j < 4; ++j) {
        int o = wave * 4 + j;
        float s = s_red[(0 * 64 + lane) * 17 + o]
                + s_red[(1 * 64 + lane) * 17 + o]
                + s_red[(2 * 64 + lane) * 17 + o]
                + s_red[(3 * 64 + lane) * 17 + o];
        out[o * DDD + gz * DD + gy * D + gx] = s;
    }
}

extern "C" void kernel_launch(void* const* d_in, const int* in_sizes, int n_in,
                              void* d_out, int out_size, void* d_ws, size_t ws_size,
                              hipStream_t stream) {
    const float* x    = (const float*)d_in[0];
    const float* kern = (const float*)d_in[1];
    const float* pk   = (const float*)d_in[2];
    float* out = (float*)d_out;

    __bf16* Wsw = (__bf16*)d_ws;                       // 86016 B
    __bf16* xcl = (__bf16*)((char*)d_ws + 131072);     // 8 MB channel-last x
    const size_t need_xcl = 131072 + (size_t)DDD * 16 * 2;
    const bool use_xcl = ws_size >= need_xcl;

    dim3 grid(8, 16, 32);
    if (use_xcl) {
        prep_fused<<<1024, 256, 0, stream>>>(x, pk, Wsw, xcl);
        deform_main<true><<<grid, 256, 0, stream>>>(x, kern, Wsw, xcl, out);
    } else {
        prep_w_only<<<21, 256, 0, stream>>>(pk, Wsw);
        deform_main<false><<<grid, 256, 0, stream>>>(x, kern, Wsw, nullptr, out);
    }
}

// Round 5
// 173.790 us; speedup vs baseline: 10.6472x; 1.1656x over previous
//
#include <hip/hip_runtime.h>

#define D 64
#define DD 4096
#define DDD 262144
#define K 27

typedef __bf16  bf16x8 __attribute__((ext_vector_type(8)));
typedef float   f32x4  __attribute__((ext_vector_type(4)));
typedef float   f32x2  __attribute__((ext_vector_type(2)));
typedef float   f32x16 __attribute__((ext_vector_type(16)));
typedef unsigned int u32x4 __attribute__((ext_vector_type(4)));

// tile 8x4x2 voxels (x,y,z); halo = tile + 2 each side
#define HX 12
#define HY 8
#define HZ 6
#define HROW 12
#define HPLN 96
#define HSP  576
#define CPAD 24          // bf16/slot: 48B = b128-aligned + 8-phase bank cycling (conflict-free)

#define WSW_CH (14*6*64)       // Wsw: 5376 chunks x 8 bf16 = 86016 B
#define KSW_CH (27*64)         // Ksw: 1728 chunks x 8 bf16 = 27648 B
#define KSW_OFF 88064          // byte offset of Ksw in d_ws

// ---------------- prep: pk -> Wsw (phase-1 A-frags), kern -> Ksw (phase-2 A-frags) ----
// Wsw chunk t=(s*6+mt)*64+lane: m=16mt+(lane&15); k=32s+8*(lane>>4)+j; W[m][k]=pk[kt][c][m], k=kt*16+c
// Ksw chunk u=kt*64+lane (32x32x16 A): m=lane&31 (o if <16 else 0-row), k=(lane>>5)*8+j=c; A=kern[kt][c][o]
__global__ __launch_bounds__(256) void prep_weights(const float* __restrict__ pk,
                                                    const float* __restrict__ kern,
                                                    __bf16* __restrict__ Wsw,
                                                    __bf16* __restrict__ Ksw) {
    int t = blockIdx.x * 256 + threadIdx.x;
    if (t < WSW_CH) {
        int lane = t & 63;
        int sm = t >> 6;
        int s = sm / 6, mt = sm - 6 * s;
        int m = mt * 16 + (lane & 15);
        int q = lane >> 4;
        bf16x8 w;
#pragma unroll
        for (int j = 0; j < 8; ++j) {
            int k = 32 * s + 8 * q + j;
            int kt = k >> 4, c = k & 15;
            float wv = (kt < K && m < 81) ? pk[kt * 1296 + c * 81 + m] : 0.0f;
            w[j] = (__bf16)wv;
        }
        *(bf16x8*)(Wsw + t * 8) = w;
    } else if (t < WSW_CH + KSW_CH) {
        int u = t - WSW_CH;
        int kt = u >> 6, lane = u & 63;
        int m = lane & 31, kh = lane >> 5;
        bf16x8 w;
#pragma unroll
        for (int j = 0; j < 8; ++j) {
            int c = kh * 8 + j;
            float wv = (m < 16) ? kern[kt * 256 + c * 16 + m] : 0.0f;
            w[j] = (__bf16)wv;
        }
        *(bf16x8*)(Ksw + u * 8) = w;
    }
}

// ---------------- main fused kernel ----------------
__global__ __launch_bounds__(256, 3) void deform_main(
    const float* __restrict__ x,          // [16][64][64][64] fp32
    const __bf16* __restrict__ Wsw,       // phase-1 A-frags
    const __bf16* __restrict__ Ksw,       // phase-2 A-frags
    float* __restrict__ out)              // [16][64][64][64]
{
    __shared__ __bf16 s_h[HSP * CPAD];    // 27648 B halo; reused for reduction
    __shared__ __bf16 s_off[81 * 64];     // 10368 B offsets bf16
    __shared__ __bf16 s_v[4 * 1024];      // 8192 B per-wave val slabs (2KB each)

    const int tid  = threadIdx.x;
    const int lane = tid & 63;
    const int wave = __builtin_amdgcn_readfirstlane(tid >> 6);

    const int bx0 = blockIdx.x * 8;
    const int by0 = blockIdx.y * 4;
    const int bz0 = blockIdx.z * 2;

    // ---- Phase 0: stage halo, fp32 -> channel-last bf16 inline ----
    for (int i = tid; i < HSP; i += 256) {
        int z = i / HPLN;
        int r = i - z * HPLN;
        int y = r / HROW;
        int xx = r - y * HROW;
        int gz = bz0 - 2 + z, gy = by0 - 2 + y, gx = bx0 - 2 + xx;
        bool in = (unsigned)gz < D && (unsigned)gy < D && (unsigned)gx < D;
        bf16x8 a = {}, b = {};
        if (in) {
            const float* p = x + (gz * DD + gy * D + gx);
#pragma unroll
            for (int c = 0; c < 8; ++c) a[c] = (__bf16)p[c * DDD];
#pragma unroll
            for (int c = 0; c < 8; ++c) b[c] = (__bf16)p[(c + 8) * DDD];
        }
        *(bf16x8*)(s_h + i * CPAD)     = a;
        *(bf16x8*)(s_h + i * CPAD + 8) = b;
    }
    __syncthreads();

    // ---- Phase 1: offset conv as bf16 MFMA implicit GEMM (M=96,K=448,N=64) ----
    {
        const int n = lane & 15, q = lane >> 4;
        const int vtz = wave >> 1;
        const int vty = 2 * (wave & 1) + (n >> 3);
        const int vtx = n & 7;
        f32x4 acc[6] = {};
        for (int s = 0; s < 14; ++s) {
            int kt = 2 * s + (q >> 1);
            int ktc = (kt < K) ? kt : 0;              // pad taps: W rows are zero
            int kd = ktc / 9, kh = (ktc / 3) % 3, kw = ktc % 3;
            int idx = (vtz + kd + 1) * HPLN + (vty + kh + 1) * HROW + (vtx + kw + 1);
            bf16x8 bfrag = *(const bf16x8*)(s_h + idx * CPAD + (q & 1) * 8);
#pragma unroll
            for (int mt = 0; mt < 6; ++mt) {
                bf16x8 afrag = *(const bf16x8*)(Wsw + ((s * 6 + mt) * 64 + lane) * 8);
                acc[mt] = __builtin_amdgcn_mfma_f32_16x16x32_bf16(afrag, bfrag, acc[mt], 0, 0, 0);
            }
        }
        const int v = wave * 16 + n;
#pragma unroll
        for (int mt = 0; mt < 6; ++mt)
#pragma unroll
            for (int r = 0; r < 4; ++r) {
                int o = mt * 16 + q * 4 + r;
                if (o < 81) s_off[o * 64 + v] = (__bf16)acc[mt][r];
            }
    }
    __syncthreads();

    // ---- Phase 2: trilinear interp (LDS) + MFMA tap/channel contraction ----
    const int tx = lane & 7, ty = (lane >> 3) & 3, tz = lane >> 5;
    const int gz = bz0 + tz, gy = by0 + ty, gx = bx0 + tx;
    const int l31 = lane & 31, lh = lane >> 5;
    __bf16* sv = s_v + wave * 1024;

    f32x16 acc2[2] = {};                  // C[o(+zero rows)][64 voxels]

    const int ntaps = (wave < 3) ? 7 : 6;
    for (int t = 0; t < ntaps; ++t) {
        const int kt = wave * 7 + t;
        const int kd = kt / 9, kh = (kt / 3) % 3, kw = kt % 3;
        float cz = (float)(gz + kd - 1) + (float)s_off[(3 * kt + 0) * 64 + lane];
        float cy = (float)(gy + kh - 1) + (float)s_off[(3 * kt + 1) * 64 + lane];
        float cx = (float)(gx + kw - 1) + (float)s_off[(3 * kt + 2) * 64 + lane];
        float zf = floorf(cz), yf = floorf(cy), xf = floorf(cx);
        float fz = cz - zf, fy = cy - yf, fx = cx - xf;
        int z0 = (int)zf, y0 = (int)yf, x0 = (int)xf;
        int hz0 = z0 - bz0 + 2, hy0 = y0 - by0 + 2, hx0 = x0 - bx0 + 2;

        f32x2 val[8] = {};
        if ((unsigned)hz0 < (unsigned)(HZ - 1) && (unsigned)hy0 < (unsigned)(HY - 1)
            && (unsigned)hx0 < (unsigned)(HX - 1)) {
#pragma unroll
            for (int dz = 0; dz < 2; ++dz) {
                float wz = dz ? fz : 1.0f - fz;
#pragma unroll
                for (int dy = 0; dy < 2; ++dy) {
                    float wzy = wz * (dy ? fy : 1.0f - fy);
#pragma unroll
                    for (int dx = 0; dx < 2; ++dx) {
                        float w = wzy * (dx ? fx : 1.0f - fx);
                        int idx = (hz0 + dz) * HPLN + (hy0 + dy) * HROW + (hx0 + dx);
                        bf16x8 c0 = *(const bf16x8*)(s_h + idx * CPAD);
                        bf16x8 c1 = *(const bf16x8*)(s_h + idx * CPAD + 8);
                        u32x4 u0 = __builtin_bit_cast(u32x4, c0);
                        u32x4 u1 = __builtin_bit_cast(u32x4, c1);
                        f32x2 w2 = {w, w};
#pragma unroll
                        for (int d = 0; d < 4; ++d) {
                            unsigned int u = u0[d];
                            f32x2 h;
                            h.x = __builtin_bit_cast(float, u << 16);
                            h.y = __builtin_bit_cast(float, u & 0xffff0000u);
                            val[d] += w2 * h;
                        }
#pragma unroll
                        for (int d = 0; d < 4; ++d) {
                            unsigned int u = u1[d];
                            f32x2 h;
                            h.x = __builtin_bit_cast(float, u << 16);
                            h.y = __builtin_bit_cast(float, u & 0xffff0000u);
                            val[d + 4] += w2 * h;
                        }
                    }
                }
            }
        } else {
            // rare: |offset| >= 1 pushed a corner outside the halo
#pragma unroll
            for (int dz = 0; dz < 2; ++dz) {
                int zi = z0 + dz;
                float wz = dz ? fz : 1.0f - fz;
#pragma unroll
                for (int dy = 0; dy < 2; ++dy) {
                    int yi = y0 + dy;
                    float wzy = wz * (dy ? fy : 1.0f - fy);
#pragma unroll
                    for (int dx = 0; dx < 2; ++dx) {
                        int xi = x0 + dx;
                        if ((unsigned)zi < D && (unsigned)yi < D && (unsigned)xi < D) {
                            float w = wzy * (dx ? fx : 1.0f - fx);
                            int base = zi * DD + yi * D + xi;
#pragma unroll
                            for (int c = 0; c < 16; ++c)
                                val[c >> 1][c & 1] += w * x[c * DDD + base];
                        }
                    }
                }
            }
        }

        // pack val -> bf16 and stash in this wave's LDS slab (lane = voxel)
        bf16x8 v0, v1;
#pragma unroll
        for (int d = 0; d < 4; ++d) { v0[2*d] = (__bf16)val[d].x;   v0[2*d+1] = (__bf16)val[d].y; }
#pragma unroll
        for (int d = 0; d < 4; ++d) { v1[2*d] = (__bf16)val[d+4].x; v1[2*d+1] = (__bf16)val[d+4].y; }
        *(bf16x8*)(sv + lane * 16)     = v0;
        *(bf16x8*)(sv + lane * 16 + 8) = v1;
        asm volatile("s_waitcnt lgkmcnt(0)" ::: "memory");  // cross-lane LDS handoff

        // A = kern tap slice (rows 16..31 zero), B = [c][voxel] from slab
        bf16x8 af = *(const bf16x8*)(Ksw + (kt * 64 + lane) * 8);
        bf16x8 b0 = *(const bf16x8*)(sv + l31 * 16 + lh * 8);
        acc2[0] = __builtin_amdgcn_mfma_f32_32x32x16_bf16(af, b0, acc2[0], 0, 0, 0);
        bf16x8 b1 = *(const bf16x8*)(sv + (32 + l31) * 16 + lh * 8);
        acc2[1] = __builtin_amdgcn_mfma_f32_32x32x16_bf16(af, b1, acc2[1], 0, 0, 0);
        asm volatile("" ::: "memory");   // keep next tap's stores after these reads
    }

    // ---- cross-wave reduction (reuse halo LDS) ----
    __syncthreads();
    float* s_red = (float*)s_h;          // [4][64][17] f32 = 17408 B
#pragma unroll
    for (int g = 0; g < 2; ++g)
#pragma unroll
        for (int r = 0; r < 8; ++r) {
            int o = (r & 3) + 8 * (r >> 2) + 4 * lh;     // 0..15
            s_red[(wave * 64 + g * 32 + l31) * 17 + o] = acc2[g][r];
        }
    __syncthreads();

#pragma unroll
    for (int j = 0; j < 4; ++j) {
        int o = wave * 4 + j;
        float s = s_red[(0 * 64 + lane) * 17 + o]
                + s_red[(1 * 64 + lane) * 17 + o]
                + s_red[(2 * 64 + lane) * 17 + o]
                + s_red[(3 * 64 + lane) * 17 + o];
        out[o * DDD + gz * DD + gy * D + gx] = s;
    }
}

extern "C" void kernel_launch(void* const* d_in, const int* in_sizes, int n_in,
                              void* d_out, int out_size, void* d_ws, size_t ws_size,
                              hipStream_t stream) {
    const float* x    = (const float*)d_in[0];
    const float* kern = (const float*)d_in[1];
    const float* pk   = (const float*)d_in[2];
    float* out = (float*)d_out;

    __bf16* Wsw = (__bf16*)d_ws;
    __bf16* Ksw = (__bf16*)((char*)d_ws + KSW_OFF);

    prep_weights<<<28, 256, 0, stream>>>(pk, kern, Wsw, Ksw);
    deform_main<<<dim3(8, 16, 32), 256, 0, stream>>>(x, Wsw, Ksw, out);
}